// Round 6
// baseline (398.663 us; speedup 1.0000x reference)
//
#include <hip/hip_runtime.h>

#define B_ 2
#define N_ 4096
#define M_ 2048
#define D_ 256
#define H_ 8
#define DH_ 32
#define ROWS_ (B_*N_)
#define KVROWS_ (B_*M_)
#define NBLK_ 1024
// SCALE * log2(e): q pre-scaled so softmax = exp2
#define PRE_ (0.17677669529663687f * 1.4426950408889634f)
#define CBASE_ 32.0f

typedef __attribute__((ext_vector_type(8))) short short8_t;
typedef __attribute__((ext_vector_type(4))) float float4_t;

#if defined(__has_builtin)
# if __has_builtin(__builtin_amdgcn_exp2f)
#  define EXP2F(x) __builtin_amdgcn_exp2f(x)
# else
#  define EXP2F(x) exp2f(x)
# endif
#else
# define EXP2F(x) exp2f(x)
#endif

// RTNE round-to-bf16 helper: rounded 32-bit word (bf16 in high half)
__device__ __forceinline__ unsigned int rne_u(float f) {
    union { float f; unsigned int u; } c;
    c.f = f;
    return c.u + 0x7FFFu + ((c.u >> 16) & 1u);
}

__device__ __forceinline__ unsigned short f2us(float f) {
    return (unsigned short)(rne_u(f) >> 16);
}

// pack two RTNE bf16: low16 = a, high16 = b  (single v_perm_b32 combine)
__device__ __forceinline__ unsigned int pack2rn(float a, float b) {
    return __builtin_amdgcn_perm(rne_u(b), rne_u(a), 0x07060302u);
}

// truncation pack (P tiles only; <=2^-8 rel err) — single v_perm_b32
__device__ __forceinline__ unsigned int pack2tr(float a, float b) {
    union { float f; unsigned int u; } x, y;
    x.f = a; y.f = b;
    return __builtin_amdgcn_perm(y.u, x.u, 0x07060302u);
}

__device__ __forceinline__ short8_t cvt8(float4 a, float4 b) {
    union { unsigned int u[4]; short8_t s; } c;
    c.u[0] = pack2rn(a.x, a.y);
    c.u[1] = pack2rn(a.z, a.w);
    c.u[2] = pack2rn(b.x, b.y);
    c.u[3] = pack2rn(b.z, b.w);
    return c.s;
}

// bijective XCD-aware block-id swizzle (valid when nwg % 8 == 0)
__device__ __forceinline__ int xcd_swz(int bid, int nwg) {
    const int cpx = nwg >> 3;
    return (bid & 7) * cpx + (bid >> 3);
}

// ---------------------------------------------------------------------------
// Stage NCOL x K fp32 weight block (source row stride LDSRC, col offset kof)
// into XOR-swizzled bf16 LDS.
// ---------------------------------------------------------------------------
template<int K, int NCOL, int LDSRC>
__device__ __forceinline__ void stageB2(const float* __restrict__ W, int col0, int kof,
                                        unsigned short* __restrict__ Bs, int tid)
{
    const int n = tid & (NCOL - 1), g = tid / NCOL;
    const int GROUPS = 256 / NCOL;
    const int CPT = (K / 8) / GROUPS;
    const float* src = W + (size_t)(col0 + n) * LDSRC + kof + g * (K / GROUPS);
#pragma unroll
    for (int ci = 0; ci < CPT; ci++) {
        int logc = g * CPT + ci;
        int phys = logc ^ (n & 7);
        short8_t v = cvt8(*(const float4*)(src + ci * 8), *(const float4*)(src + ci * 8 + 4));
        *(short8_t*)(Bs + (size_t)n * K + phys * 8) = v;
    }
}

template<int K>
__device__ __forceinline__ short8_t readB(const unsigned short* __restrict__ Bs,
                                          int c, int l16, int quad, int k0)
{
    int phys = ((k0 >> 3) + quad) ^ (l16 & 7);
    return *(const short8_t*)(Bs + (size_t)(16 * c + l16) * K + phys * 8);
}

// ---------------------------------------------------------------------------
struct P_t {
    const float *points, *voxel, *Wp, *bp, *Wq, *bq, *Wk, *bk, *Wv, *bv, *Wf, *bfb;
    unsigned short *k_g, *vt_g, *att_g;
    float *Wqc, *Wfc, *out;
    unsigned int *sem;
};

// ---------------------------------------------------------------------------
// Device-scope grid barrier. SAFE by construction: grid=1024 blocks, LDS
// 32KB + VGPR<=128 (launch_bounds(256,4)) -> capacity >= 4/CU * 256 CU =
// 1024 = grid, so all blocks co-resident; spin cannot deadlock.
// Producer side: __syncthreads (compiler emits vmcnt drain) -> stores in L2;
// thread0's __threadfence emits cache-wide wbl2 (device visibility), then
// device-scope atomicAdd. Consumer: relaxed agent poll, then __threadfence
// (cache-wide inv) before releasing the block.
// ---------------------------------------------------------------------------
__device__ __forceinline__ void gbar(unsigned int* sem, int idx) {
    __syncthreads();
    if (threadIdx.x == 0) {
        __threadfence();
        atomicAdd(&sem[idx], 1u);
        while (__hip_atomic_load(&sem[idx], __ATOMIC_RELAXED,
                                 __HIP_MEMORY_SCOPE_AGENT) < (unsigned)NBLK_) {
            __builtin_amdgcn_s_sleep(8);
        }
        __threadfence();
    }
    __syncthreads();
}

// ---------------------------------------------------------------------------
// Phase A: KV projection over ALL 1024 blocks + weight-fold prep.
// Tile = 32 rows x 32 cols, BOTH Wk and Wv staged (16KB+16KB LDS).
// Wave w: rows row0+(w&1)*16, weight = (w>>1)? Wv : Wk.
// Blocks [0,256): also fold Wqc[bid]; [256,512): Wfc[bid-256] (wave 0,
// butterfly reduce, no LDS).
// ---------------------------------------------------------------------------
__device__ __forceinline__ void phase_proj(int bid, int tid,
                                           unsigned short* __restrict__ S, const P_t& p)
{
    const int w = tid >> 6, lane = tid & 63, quad = lane >> 4, l16 = lane & 15;
    const int row0 = (bid >> 3) * 32;     // 128 row-tiles of 32 KV rows
    const int col0 = (bid & 7) * 32;      // 8 col-slices

    unsigned short* BsK = S;              // [32][256] bf16 = 16 KB
    unsigned short* BsV = S + 8192;       // [32][256] bf16 = 16 KB

    stageB2<256, 32, 256>(p.Wk, col0, 0, BsK, tid);
    stageB2<256, 32, 256>(p.Wv, col0, 0, BsV, tid);

    const int myrow = row0 + (w & 1) * 16 + l16;
    const float* arow = p.voxel + (size_t)myrow * D_;
    short8_t af[8];
#pragma unroll
    for (int i = 0; i < 8; i++)
        af[i] = cvt8(*(const float4*)(arow + i * 32 + quad * 8),
                     *(const float4*)(arow + i * 32 + quad * 8 + 4));

    const unsigned short* ws = (w >> 1) ? BsV : BsK;
    float4_t acc[2];
#pragma unroll
    for (int c = 0; c < 2; c++) acc[c] = (float4_t){0.f, 0.f, 0.f, 0.f};
    __syncthreads();
#pragma unroll
    for (int i = 0; i < 8; i++)
#pragma unroll
        for (int c = 0; c < 2; c++)
            acc[c] = __builtin_amdgcn_mfma_f32_16x16x32_bf16(af[i], readB<256>(ws, c, l16, quad, i * 32), acc[c], 0, 0, 0);

    if (w < 2) {
        // K epilogue
#pragma unroll
        for (int c = 0; c < 2; c++) {
            int col = col0 + 16 * c + l16;
            float bbk = p.bk[col];
#pragma unroll
            for (int r = 0; r < 4; r++) {
                int row = row0 + (w & 1) * 16 + quad * 4 + r;
                p.k_g[(size_t)row * D_ + col] = f2us(acc[c][r] + bbk);
            }
        }
    } else {
        // V epilogue (transposed store)
        const int b = row0 / M_;
        const int m0 = row0 - b * M_ + (w & 1) * 16 + quad * 4;
#pragma unroll
        for (int c = 0; c < 2; c++) {
            int col = col0 + 16 * c + l16;
            float bbv = p.bv[col];
            int h = col >> 5, dh = col & 31;
            unsigned int u0 = pack2rn(acc[c][0] + bbv, acc[c][1] + bbv);
            unsigned int u1 = pack2rn(acc[c][2] + bbv, acc[c][3] + bbv);
            *(uint2*)(p.vt_g + (size_t)((b * H_ + h) * DH_ + dh) * M_ + m0) = make_uint2(u0, u1);
        }
    }

    // ---- fold prep: Wqc (blocks 0..255) / Wfc (blocks 256..511), wave 0 ----
    if (bid < 512 && w == 0) {
        const int col = bid & 255;
        const bool isQ = (bid < 256);
        const float* wrow = isQ ? (p.Wq + (size_t)col * 256) : (p.Wf + (size_t)col * 512);
        float a0 = 0.f, a1 = 0.f, a2 = 0.f, ab = 0.f;
#pragma unroll
        for (int i = 0; i < 4; i++) {
            int t = i * 64 + lane;
            float wv = wrow[t];
            a0 += wv * p.Wp[t * 3 + 0];
            a1 += wv * p.Wp[t * 3 + 1];
            a2 += wv * p.Wp[t * 3 + 2];
            ab += wv * p.bp[t];
        }
#pragma unroll
        for (int m = 1; m < 64; m <<= 1) {
            a0 += __shfl_xor(a0, m);
            a1 += __shfl_xor(a1, m);
            a2 += __shfl_xor(a2, m);
            ab += __shfl_xor(ab, m);
        }
        if (lane == 0) {
            if (isQ)
                *(float4*)(p.Wqc + (size_t)col * 4) =
                    make_float4(a0 * PRE_, a1 * PRE_, a2 * PRE_, (ab + p.bq[col]) * PRE_);
            else
                *(float4*)(p.Wfc + (size_t)col * 4) =
                    make_float4(a0, a1, a2, ab + p.bfb[col]);
        }
    }
}

// ---------------------------------------------------------------------------
// Phase B: MFMA flash attention (r5 k_attn9, S-offset LDS).
// Permuted K-row QK^T -> MFMA outputs land directly in PV B-fragment order
// (no P LDS round-trip). K rows stored at rho(kv)=kv^((kv&8)>>1).
// LDS: Kt 2x64x40 @0 (5120 sh), Vt 2x32x72 @5120 (4608 sh) = 19.5 KB.
// ---------------------------------------------------------------------------
__device__ __forceinline__ void phase_attn(int bid, int tid,
                                           unsigned short* __restrict__ S, const P_t& p)
{
    const int w = tid >> 6, lane = tid & 63, quad = lane >> 4, l16 = lane & 15;
    const int lbid = xcd_swz(bid, NBLK_);
    const int nt = lbid & 63;             // N/64
    const int bh = lbid >> 6;             // b*8+h
    const int b = bh >> 3, h = bh & 7;
    const int n0 = nt * 64 + w * 16;

    unsigned short* Kt = S;               // [2][64][40]
    unsigned short* Vt = S + 5120;        // [2][32][72]

    const unsigned short* kbase = p.k_g + (size_t)(b * M_) * D_ + h * DH_;
    const unsigned short* vbase = p.vt_g + (size_t)(bh * DH_) * M_;

    // staging roles
    const int kr = tid >> 2, kc = tid & 3;   // K: 64 rows x 4 chunks
    const int vr = tid >> 3, vc = tid & 7;   // V: 32 rows x 8 chunks
    const int ksr = kr ^ ((kr & 8) >> 1);    // rho-permuted LDS row for K

    const unsigned short* kq = kbase + (size_t)kr * D_ + kc * 8;
    const unsigned short* vq = vbase + (size_t)vr * M_ + vc * 8;

    // prologue: stage step 0 into buf 0
    *(short8_t*)(Kt + ksr * 40 + kc * 8) = *(const short8_t*)kq;
    *(short8_t*)(Vt + vr * 72 + vc * 8) = *(const short8_t*)vq;

    // permuted K-row read indices (rho applied; XOR safe: bit2 never carries)
    const int rbas = 8 * (l16 >> 2) + (l16 & 3);
    const int rx = l16 & 4;
    int krow[4];
#pragma unroll
    for (int t = 0; t < 4; t++)
        krow[t] = (rbas + 4 * (t & 1) + 32 * (t >> 1)) ^ rx;

    // q inline: row = b*N_ + n0 + l16, cols h*32 + quad*8 + j  (f32-exact)
    const size_t qrow = (size_t)(b * N_ + n0 + l16);
    const float p0 = p.points[qrow * 3 + 0];
    const float p1 = p.points[qrow * 3 + 1];
    const float p2 = p.points[qrow * 3 + 2];
    float q8[8];
#pragma unroll
    for (int j = 0; j < 8; j++) {
        float4 wc = *(const float4*)(p.Wqc + (size_t)(h * DH_ + quad * 8 + j) * 4);
        q8[j] = p0 * wc.x + p1 * wc.y + p2 * wc.z + wc.w;
    }
    short8_t qf = cvt8(make_float4(q8[0], q8[1], q8[2], q8[3]),
                       make_float4(q8[4], q8[5], q8[6], q8[7]));

    float4_t od0 = {0.f, 0.f, 0.f, 0.f};
    float4_t od1 = {0.f, 0.f, 0.f, 0.f};
    float l_lane = 0.f;

    const float4_t zc = {-CBASE_, -CBASE_, -CBASE_, -CBASE_};

#pragma unroll 2
    for (int s = 0; s < M_ / 64; s++) {
        __syncthreads();
        const int buf = s & 1;
        const bool more = (s + 1 < M_ / 64);
        short8_t knext, vnext;
        if (more) {
            kq += 64 * D_;
            vq += 64;
            knext = *(const short8_t*)kq;
            vnext = *(const short8_t*)vq;
        }

        float4_t st[4];
#pragma unroll
        for (int t = 0; t < 4; t++) {
            short8_t kf = *(const short8_t*)(Kt + buf * 2560 + krow[t] * 40 + quad * 8);
            st[t] = __builtin_amdgcn_mfma_f32_16x16x32_bf16(kf, qf, zc, 0, 0, 0);
        }

        float psum = 0.f;
        unsigned int uu[4][2];
#pragma unroll
        for (int t = 0; t < 4; t++) {
            float p0e = EXP2F(st[t][0]);
            float p1e = EXP2F(st[t][1]);
            float p2e = EXP2F(st[t][2]);
            float p3e = EXP2F(st[t][3]);
            psum += (p0e + p1e) + (p2e + p3e);
            uu[t][0] = pack2tr(p0e, p1e);
            uu[t][1] = pack2tr(p2e, p3e);
        }
        l_lane += psum;

        union { unsigned int u[4]; short8_t s; } pa, pb2;
        pa.u[0]  = uu[0][0]; pa.u[1]  = uu[0][1]; pa.u[2]  = uu[1][0]; pa.u[3]  = uu[1][1];
        pb2.u[0] = uu[2][0]; pb2.u[1] = uu[2][1]; pb2.u[2] = uu[3][0]; pb2.u[3] = uu[3][1];

        short8_t vf00 = *(const short8_t*)(Vt + buf * 2304 + l16 * 72 + quad * 8);
        short8_t vf01 = *(const short8_t*)(Vt + buf * 2304 + l16 * 72 + 32 + quad * 8);
        short8_t vf10 = *(const short8_t*)(Vt + buf * 2304 + (16 + l16) * 72 + quad * 8);
        short8_t vf11 = *(const short8_t*)(Vt + buf * 2304 + (16 + l16) * 72 + 32 + quad * 8);
        od0 = __builtin_amdgcn_mfma_f32_16x16x32_bf16(vf00, pa.s,  od0, 0, 0, 0);
        od0 = __builtin_amdgcn_mfma_f32_16x16x32_bf16(vf01, pb2.s, od0, 0, 0, 0);
        od1 = __builtin_amdgcn_mfma_f32_16x16x32_bf16(vf10, pa.s,  od1, 0, 0, 0);
        od1 = __builtin_amdgcn_mfma_f32_16x16x32_bf16(vf11, pb2.s, od1, 0, 0, 0);

        if (more) {
            *(short8_t*)(Kt + (buf ^ 1) * 2560 + ksr * 40 + kc * 8) = knext;
            *(short8_t*)(Vt + (buf ^ 1) * 2304 + vr * 72 + vc * 8) = vnext;
        }
    }

    l_lane += __shfl_xor(l_lane, 16);
    l_lane += __shfl_xor(l_lane, 32);
    const float inv = 1.0f / l_lane;

    unsigned short* ob = p.att_g + (size_t)(b * N_ + n0 + l16) * D_ + h * DH_;
    {
        unsigned int u0 = pack2rn(od0[0] * inv, od0[1] * inv);
        unsigned int u1 = pack2rn(od0[2] * inv, od0[3] * inv);
        *(uint2*)(ob + quad * 4) = make_uint2(u0, u1);
        unsigned int u2 = pack2rn(od1[0] * inv, od1[1] * inv);
        unsigned int u3 = pack2rn(od1[2] * inv, od1[3] * inv);
        *(uint2*)(ob + 16 + quad * 4) = make_uint2(u2, u3);
    }
}

// ---------------------------------------------------------------------------
// Phase C: fuse GEMM out = att@Wf2.T + points@Wfc.T (bias folded), fp32 out.
// ---------------------------------------------------------------------------
__device__ __forceinline__ void phase_fuse(int bid, int tid,
                                           unsigned short* __restrict__ S, const P_t& p)
{
    const int wave = tid >> 6, lane = tid & 63, quad = lane >> 4, l16 = lane & 15;
    const int lbid = xcd_swz(bid, NBLK_);
    const int row0 = (lbid >> 3) * 64;
    const int col0 = (lbid & 7) * 32;

    stageB2<256, 32, 512>(p.Wf, col0, 256, S, tid);
    __syncthreads();

    float4_t acc[2];
#pragma unroll
    for (int c = 0; c < 2; c++) acc[c] = (float4_t){0.f, 0.f, 0.f, 0.f};

    const size_t arow = (size_t)(row0 + wave * 16 + l16) * D_;
#pragma unroll
    for (int k0 = 0; k0 < 256; k0 += 32) {
        short8_t af = *(const short8_t*)(p.att_g + arow + k0 + quad * 8);
#pragma unroll
        for (int c = 0; c < 2; c++)
            acc[c] = __builtin_amdgcn_mfma_f32_16x16x32_bf16(af, readB<256>(S, c, l16, quad, k0), acc[c], 0, 0, 0);
    }

    const int rbase = row0 + wave * 16 + quad * 4;
    float px[4], py[4], pz[4];
#pragma unroll
    for (int r = 0; r < 4; r++) {
        px[r] = p.points[(size_t)(rbase + r) * 3 + 0];
        py[r] = p.points[(size_t)(rbase + r) * 3 + 1];
        pz[r] = p.points[(size_t)(rbase + r) * 3 + 2];
    }
#pragma unroll
    for (int c = 0; c < 2; c++) {
        int col = col0 + 16 * c + l16;
        float4 wf = *(const float4*)(p.Wfc + (size_t)col * 4);
#pragma unroll
        for (int r = 0; r < 4; r++) {
            p.out[(size_t)(rbase + r) * D_ + col] =
                acc[c][r] + px[r] * wf.x + py[r] * wf.y + pz[r] * wf.z + wf.w;
        }
    }
}

// ---------------------------------------------------------------------------
// Fused kernel: proj -> gbar -> attn -> gbar -> fuse. 1024 blocks x 256 thr,
// 32KB LDS, VGPR<=128 -> all blocks co-resident (spin barrier safe).
// ---------------------------------------------------------------------------
__global__ __launch_bounds__(256, 4) void k_fused(P_t p)
{
    __shared__ __align__(16) unsigned short S[16384];  // 32 KB
    const int bid = (int)blockIdx.x, tid = (int)threadIdx.x;

    phase_proj(bid, tid, S, p);
    gbar(p.sem, 0);
    phase_attn(bid, tid, S, p);
    gbar(p.sem, 1);
    phase_fuse(bid, tid, S, p);
}

// ---------------------------------------------------------------------------
extern "C" void kernel_launch(void* const* d_in, const int* in_sizes, int n_in,
                              void* d_out, int out_size, void* d_ws, size_t ws_size,
                              hipStream_t stream)
{
    P_t p;
    p.points = (const float*)d_in[0];
    p.voxel  = (const float*)d_in[1];
    p.Wp  = (const float*)d_in[2];
    p.bp  = (const float*)d_in[3];
    p.Wq  = (const float*)d_in[4];
    p.bq  = (const float*)d_in[5];
    p.Wk  = (const float*)d_in[6];
    p.bk  = (const float*)d_in[7];
    p.Wv  = (const float*)d_in[8];
    p.bv  = (const float*)d_in[9];
    p.Wf  = (const float*)d_in[10];
    p.bfb = (const float*)d_in[11];
    p.out = (float*)d_out;

    p.sem = (unsigned int*)d_ws;                       // 2 counters (zeroed below)
    p.Wqc = (float*)d_ws + 16;                         // [256][4] f32
    p.Wfc = p.Wqc + 256 * 4;                           // [256][4] f32
    p.k_g   = (unsigned short*)(p.Wfc + 256 * 4);
    p.vt_g  = p.k_g  + (size_t)KVROWS_ * D_;           // [b][h][dh][m]
    p.att_g = p.vt_g + (size_t)KVROWS_ * D_;

    hipMemsetAsync(d_ws, 0, 64, stream);               // zero barrier counters
    k_fused<<<dim3(NBLK_), dim3(256), 0, stream>>>(p);
}

// Round 7
// 133.862 us; speedup vs baseline: 2.9782x; 2.9782x over previous
//
#include <hip/hip_runtime.h>

#define B_ 2
#define N_ 4096
#define M_ 2048
#define D_ 256
#define H_ 8
#define DH_ 32
#define ROWS_ (B_*N_)
#define KVROWS_ (B_*M_)
// SCALE * log2(e): q pre-scaled so softmax = exp2
#define PRE_ (0.17677669529663687f * 1.4426950408889634f)
#define CBASE_ 32.0f

typedef __attribute__((ext_vector_type(8))) short short8_t;
typedef __attribute__((ext_vector_type(4))) float float4_t;

#if defined(__has_builtin)
# if __has_builtin(__builtin_amdgcn_exp2f)
#  define EXP2F(x) __builtin_amdgcn_exp2f(x)
# else
#  define EXP2F(x) exp2f(x)
# endif
#else
# define EXP2F(x) exp2f(x)
#endif

// RTNE round-to-bf16 helper: rounded 32-bit word (bf16 in high half)
__device__ __forceinline__ unsigned int rne_u(float f) {
    union { float f; unsigned int u; } c;
    c.f = f;
    return c.u + 0x7FFFu + ((c.u >> 16) & 1u);
}

__device__ __forceinline__ unsigned short f2us(float f) {
    return (unsigned short)(rne_u(f) >> 16);
}

// pack two RTNE bf16: low16 = a, high16 = b  (single v_perm_b32 combine)
__device__ __forceinline__ unsigned int pack2rn(float a, float b) {
    return __builtin_amdgcn_perm(rne_u(b), rne_u(a), 0x07060302u);
}

// truncation pack (P tiles only; <=2^-8 rel err) — single v_perm_b32
__device__ __forceinline__ unsigned int pack2tr(float a, float b) {
    union { float f; unsigned int u; } x, y;
    x.f = a; y.f = b;
    return __builtin_amdgcn_perm(y.u, x.u, 0x07060302u);
}

__device__ __forceinline__ short8_t cvt8(float4 a, float4 b) {
    union { unsigned int u[4]; short8_t s; } c;
    c.u[0] = pack2rn(a.x, a.y);
    c.u[1] = pack2rn(a.z, a.w);
    c.u[2] = pack2rn(b.x, b.y);
    c.u[3] = pack2rn(b.z, b.w);
    return c.s;
}

// bijective XCD-aware block-id swizzle (valid when nwg % 8 == 0)
__device__ __forceinline__ int xcd_swz(int bid, int nwg) {
    const int cpx = nwg >> 3;
    return (bid & 7) * cpx + (bid >> 3);
}

// ---------------------------------------------------------------------------
// Stage NCOL x K fp32 weight block (source row stride LDSRC, col offset kof)
// into XOR-swizzled bf16 LDS.
// ---------------------------------------------------------------------------
template<int K, int NCOL, int LDSRC>
__device__ __forceinline__ void stageB2(const float* __restrict__ W, int col0, int kof,
                                        unsigned short* __restrict__ Bs, int tid)
{
    const int n = tid & (NCOL - 1), g = tid / NCOL;
    const int GROUPS = 256 / NCOL;
    const int CPT = (K / 8) / GROUPS;
    const float* src = W + (size_t)(col0 + n) * LDSRC + kof + g * (K / GROUPS);
#pragma unroll
    for (int ci = 0; ci < CPT; ci++) {
        int logc = g * CPT + ci;
        int phys = logc ^ (n & 7);
        short8_t v = cvt8(*(const float4*)(src + ci * 8), *(const float4*)(src + ci * 8 + 4));
        *(short8_t*)(Bs + (size_t)n * K + phys * 8) = v;
    }
}

template<int K>
__device__ __forceinline__ short8_t readB(const unsigned short* __restrict__ Bs,
                                          int c, int l16, int quad, int k0)
{
    int phys = ((k0 >> 3) + quad) ^ (l16 & 7);
    return *(const short8_t*)(Bs + (size_t)(16 * c + l16) * K + phys * 8);
}

// ---------------------------------------------------------------------------
// KV projection + weight-fold prep, occupancy-tiled.
// blocks [0,512): tile = 64 rows x 64 cols, K OR V (split -> 32KB LDS,
//   2 blocks/CU vs r5's 1). lbid layout (row,col,kv): the 8 blocks sharing a
//   64-row voxel panel are CONSECUTIVE -> xcd_swz puts them on one XCD L2.
// block 512: Wqc[256][4] = PRE_*(Wq@Wp | Wq@bp+bq)
// block 513: Wfc[256][4] = (Wf1@Wp | Wf1@bp+bf)
// ---------------------------------------------------------------------------
__global__ __launch_bounds__(256) void g_projkv4(
    const float* __restrict__ voxel,
    const float* __restrict__ Wp, const float* __restrict__ bp,
    const float* __restrict__ Wq, const float* __restrict__ bq,
    const float* __restrict__ Wk, const float* __restrict__ bk,
    const float* __restrict__ Wv, const float* __restrict__ bv,
    const float* __restrict__ Wf, const float* __restrict__ bfb,
    unsigned short* __restrict__ k_g, unsigned short* __restrict__ vt_g,
    float* __restrict__ Wqc, float* __restrict__ Wfc)
{
    const int tid = threadIdx.x;
    const int wave = tid >> 6, lane = tid & 63, quad = lane >> 4, l16 = lane & 15;

    __shared__ unsigned short Bs[64 * 256];   // 32 KB

    const int bid = (int)blockIdx.x;
    if (bid < 512) {
        const int lbid = xcd_swz(bid, 512);
        const int row0 = (lbid >> 3) * 64;
        const int sub  = lbid & 7;
        const int col0 = (sub >> 1) * 64;
        const bool isV = sub & 1;

        stageB2<256, 64, 256>(isV ? Wv : Wk, col0, 0, Bs, tid);

        const float* arow = voxel + (size_t)(row0 + wave * 16 + l16) * D_;
        short8_t af[8];
#pragma unroll
        for (int i = 0; i < 8; i++)
            af[i] = cvt8(*(const float4*)(arow + i * 32 + quad * 8),
                         *(const float4*)(arow + i * 32 + quad * 8 + 4));

        float4_t acc[4];
#pragma unroll
        for (int c = 0; c < 4; c++) acc[c] = (float4_t){0.f, 0.f, 0.f, 0.f};
        __syncthreads();
#pragma unroll
        for (int i = 0; i < 8; i++)
#pragma unroll
            for (int c = 0; c < 4; c++)
                acc[c] = __builtin_amdgcn_mfma_f32_16x16x32_bf16(af[i], readB<256>(Bs, c, l16, quad, i * 32), acc[c], 0, 0, 0);

        if (!isV) {
#pragma unroll
            for (int c = 0; c < 4; c++) {
                int col = col0 + 16 * c + l16;
                float bbk = bk[col];
#pragma unroll
                for (int r = 0; r < 4; r++) {
                    int row = row0 + wave * 16 + quad * 4 + r;
                    k_g[(size_t)row * D_ + col] = f2us(acc[c][r] + bbk);
                }
            }
        } else {
            const int b = row0 / M_;
            const int m0 = row0 - b * M_ + wave * 16 + quad * 4;
#pragma unroll
            for (int c = 0; c < 4; c++) {
                int col = col0 + 16 * c + l16;
                float bbv = bv[col];
                int h = col >> 5, dh = col & 31;
                unsigned int u0 = pack2rn(acc[c][0] + bbv, acc[c][1] + bbv);
                unsigned int u1 = pack2rn(acc[c][2] + bbv, acc[c][3] + bbv);
                *(uint2*)(vt_g + (size_t)((b * H_ + h) * DH_ + dh) * M_ + m0) = make_uint2(u0, u1);
            }
        }
    } else {
        // ---- prep role: fold fan-in-3 weights in f32 (exact) ----
        const int role = bid - 512;               // 0: Wqc, 1: Wfc
        float* wps = (float*)Bs;                  // [256][4] staged Wp|bp
        *(float4*)(wps + tid * 4) = make_float4(Wp[tid * 3 + 0], Wp[tid * 3 + 1],
                                                Wp[tid * 3 + 2], bp[tid]);
        __syncthreads();
        const int col = tid;
        const float* wrow = role ? (Wf + (size_t)col * 512) : (Wq + (size_t)col * 256);
        float a0 = 0.f, a1 = 0.f, a2 = 0.f, ab = 0.f;
#pragma unroll 4
        for (int d = 0; d < 256; d += 4) {
            float4 wv = *(const float4*)(wrow + d);
            float4 w0 = *(const float4*)(wps + (d + 0) * 4);
            float4 w1 = *(const float4*)(wps + (d + 1) * 4);
            float4 w2 = *(const float4*)(wps + (d + 2) * 4);
            float4 w3 = *(const float4*)(wps + (d + 3) * 4);
            a0 += wv.x * w0.x + wv.y * w1.x + wv.z * w2.x + wv.w * w3.x;
            a1 += wv.x * w0.y + wv.y * w1.y + wv.z * w2.y + wv.w * w3.y;
            a2 += wv.x * w0.z + wv.y * w1.z + wv.z * w2.z + wv.w * w3.z;
            ab += wv.x * w0.w + wv.y * w1.w + wv.z * w2.w + wv.w * w3.w;
        }
        if (role == 0) {
            *(float4*)(Wqc + (size_t)col * 4) =
                make_float4(a0 * PRE_, a1 * PRE_, a2 * PRE_, (ab + bq[col]) * PRE_);
        } else {
            *(float4*)(Wfc + (size_t)col * 4) =
                make_float4(a0, a1, a2, ab + bfb[col]);
        }
    }
}

// ---------------------------------------------------------------------------
// MFMA flash attention v10: 128 q-rows/block, 512 threads (8 waves).
// Per-wave math is BIT-IDENTICAL to r5's k_attn9 (permuted-K QK^T -> P in
// PV B-fragment order, no P LDS round-trip). What changed: K/V staging is
// amortized over 2x the q-rows — each thread does exactly ONE 16B stage per
// step (waves 0-3: K, waves 4-7: V; wave-uniform, no divergence).
// Grid 512 -> 2 blocks/CU x 8 waves = 16 waves/CU (same occupancy as r5).
// ---------------------------------------------------------------------------
__global__ __launch_bounds__(512) void k_attn10(
    const float* __restrict__ points, const float* __restrict__ Wqc,
    const unsigned short* __restrict__ k_g,
    const unsigned short* __restrict__ vt_g,
    unsigned short* __restrict__ att_g)
{
    const int tid = threadIdx.x;
    const int w = tid >> 6, lane = tid & 63, quad = lane >> 4, l16 = lane & 15;
    const int lbid = xcd_swz((int)blockIdx.x, B_ * H_ * (N_ / 128));
    const int nt = lbid & 31;             // N/128
    const int bh = lbid >> 5;             // b*8+h
    const int b = bh >> 3, h = bh & 7;
    const int n0 = nt * 128 + w * 16;

    __shared__ unsigned short Kt[2][64][40];   // 10.2 KB
    __shared__ unsigned short Vt[2][32][72];   //  9.2 KB

    const unsigned short* kbase = k_g + (size_t)(b * M_) * D_ + h * DH_;
    const unsigned short* vbase = vt_g + (size_t)(bh * DH_) * M_;

    // staging role: one 16B chunk per thread per step
    const bool isK = (tid < 256);
    const int kr = tid >> 2, kc = tid & 3;            // K: 64 rows x 4 chunks
    const int vr = (tid - 256) >> 3, vc = tid & 7;    // V: 32 rows x 8 chunks
    const int ksr = kr ^ ((kr & 8) >> 1);             // rho-permuted K LDS row

    const unsigned short* gq = isK ? (kbase + (size_t)kr * D_ + kc * 8)
                                   : (vbase + (size_t)vr * M_ + vc * 8);
    const int gstep = isK ? 64 * D_ : 64;
    unsigned short* ldst = isK ? (&Kt[0][0][0] + ksr * 40 + kc * 8)
                               : (&Vt[0][0][0] + vr * 72 + vc * 8);
    const int lstride = isK ? 2560 : 2304;            // buf stride in shorts

    // prologue: stage step 0 into buf 0
    *(short8_t*)ldst = *(const short8_t*)gq;

    // permuted K-row read indices (rho applied; XOR safe: bit2 never carries)
    const int rbas = 8 * (l16 >> 2) + (l16 & 3);
    const int rx = l16 & 4;
    int krow[4];
#pragma unroll
    for (int t = 0; t < 4; t++)
        krow[t] = (rbas + 4 * (t & 1) + 32 * (t >> 1)) ^ rx;

    // q inline: row = b*N_ + n0 + l16, cols h*32 + quad*8 + j  (f32-exact)
    const size_t qrow = (size_t)(b * N_ + n0 + l16);
    const float p0 = points[qrow * 3 + 0];
    const float p1 = points[qrow * 3 + 1];
    const float p2 = points[qrow * 3 + 2];
    float q8[8];
#pragma unroll
    for (int j = 0; j < 8; j++) {
        float4 wc = *(const float4*)(Wqc + (size_t)(h * DH_ + quad * 8 + j) * 4);
        q8[j] = p0 * wc.x + p1 * wc.y + p2 * wc.z + wc.w;
    }
    short8_t qf = cvt8(make_float4(q8[0], q8[1], q8[2], q8[3]),
                       make_float4(q8[4], q8[5], q8[6], q8[7]));

    float4_t od0 = {0.f, 0.f, 0.f, 0.f};
    float4_t od1 = {0.f, 0.f, 0.f, 0.f};
    float l_lane = 0.f;

    const float4_t zc = {-CBASE_, -CBASE_, -CBASE_, -CBASE_};

#pragma unroll 2
    for (int s = 0; s < M_ / 64; s++) {
        __syncthreads();
        const int buf = s & 1;
        const bool more = (s + 1 < M_ / 64);
        short8_t nxt;
        if (more) {
            gq += gstep;
            nxt = *(const short8_t*)gq;
        }

        float4_t st[4];
#pragma unroll
        for (int t = 0; t < 4; t++) {
            short8_t kf = *(const short8_t*)&Kt[buf][krow[t]][quad * 8];
            st[t] = __builtin_amdgcn_mfma_f32_16x16x32_bf16(kf, qf, zc, 0, 0, 0);
        }

        float psum = 0.f;
        unsigned int uu[4][2];
#pragma unroll
        for (int t = 0; t < 4; t++) {
            float p0e = EXP2F(st[t][0]);
            float p1e = EXP2F(st[t][1]);
            float p2e = EXP2F(st[t][2]);
            float p3e = EXP2F(st[t][3]);
            psum += (p0e + p1e) + (p2e + p3e);
            uu[t][0] = pack2tr(p0e, p1e);
            uu[t][1] = pack2tr(p2e, p3e);
        }
        l_lane += psum;

        union { unsigned int u[4]; short8_t s; } pa, pb2;
        pa.u[0]  = uu[0][0]; pa.u[1]  = uu[0][1]; pa.u[2]  = uu[1][0]; pa.u[3]  = uu[1][1];
        pb2.u[0] = uu[2][0]; pb2.u[1] = uu[2][1]; pb2.u[2] = uu[3][0]; pb2.u[3] = uu[3][1];

        short8_t vf00 = *(const short8_t*)&Vt[buf][l16][quad * 8];
        short8_t vf01 = *(const short8_t*)&Vt[buf][l16][32 + quad * 8];
        short8_t vf10 = *(const short8_t*)&Vt[buf][16 + l16][quad * 8];
        short8_t vf11 = *(const short8_t*)&Vt[buf][16 + l16][32 + quad * 8];
        od0 = __builtin_amdgcn_mfma_f32_16x16x32_bf16(vf00, pa.s,  od0, 0, 0, 0);
        od0 = __builtin_amdgcn_mfma_f32_16x16x32_bf16(vf01, pb2.s, od0, 0, 0, 0);
        od1 = __builtin_amdgcn_mfma_f32_16x16x32_bf16(vf10, pa.s,  od1, 0, 0, 0);
        od1 = __builtin_amdgcn_mfma_f32_16x16x32_bf16(vf11, pb2.s, od1, 0, 0, 0);

        if (more)
            *(short8_t*)(ldst + (buf ^ 1) * lstride) = nxt;
    }

    l_lane += __shfl_xor(l_lane, 16);
    l_lane += __shfl_xor(l_lane, 32);
    const float inv = 1.0f / l_lane;

    unsigned short* ob = att_g + (size_t)(b * N_ + n0 + l16) * D_ + h * DH_;
    {
        unsigned int u0 = pack2rn(od0[0] * inv, od0[1] * inv);
        unsigned int u1 = pack2rn(od0[2] * inv, od0[3] * inv);
        *(uint2*)(ob + quad * 4) = make_uint2(u0, u1);
        unsigned int u2 = pack2rn(od1[0] * inv, od1[1] * inv);
        unsigned int u3 = pack2rn(od1[2] * inv, od1[3] * inv);
        *(uint2*)(ob + 16 + quad * 4) = make_uint2(u2, u3);
    }
}

// ---------------------------------------------------------------------------
// Fuse: out = att@Wf2.T + points@Wfc.T (bias folded), fp32 out.
// 64x64 tiles (512 blocks): att_g re-read 4x instead of 8x.
// ---------------------------------------------------------------------------
__global__ __launch_bounds__(256) void g_fuse3(
    const unsigned short* __restrict__ att_g,
    const float* __restrict__ points, const float* __restrict__ Wfc,
    const float* __restrict__ Wf,
    float* __restrict__ out)
{
    const int tid = threadIdx.x;
    const int wave = tid >> 6, lane = tid & 63, quad = lane >> 4, l16 = lane & 15;
    const int lbid = xcd_swz((int)blockIdx.x, (ROWS_ / 64) * 4);
    const int row0 = (lbid >> 2) * 64;
    const int col0 = (lbid & 3) * 64;

    __shared__ unsigned short Bs[64 * 256];  // 32 KB (Wf cols 256..511)

    stageB2<256, 64, 512>(Wf, col0, 256, Bs, tid);
    __syncthreads();

    float4_t acc[4];
#pragma unroll
    for (int c = 0; c < 4; c++) acc[c] = (float4_t){0.f, 0.f, 0.f, 0.f};

    const size_t arow = (size_t)(row0 + wave * 16 + l16) * D_;
#pragma unroll
    for (int k0 = 0; k0 < 256; k0 += 32) {
        short8_t af = *(const short8_t*)(att_g + arow + k0 + quad * 8);
#pragma unroll
        for (int c = 0; c < 4; c++)
            acc[c] = __builtin_amdgcn_mfma_f32_16x16x32_bf16(af, readB<256>(Bs, c, l16, quad, k0), acc[c], 0, 0, 0);
    }

    const int rbase = row0 + wave * 16 + quad * 4;
    float px[4], py[4], pz[4];
#pragma unroll
    for (int r = 0; r < 4; r++) {
        px[r] = points[(size_t)(rbase + r) * 3 + 0];
        py[r] = points[(size_t)(rbase + r) * 3 + 1];
        pz[r] = points[(size_t)(rbase + r) * 3 + 2];
    }
#pragma unroll
    for (int c = 0; c < 4; c++) {
        int col = col0 + 16 * c + l16;
        float4 wf = *(const float4*)(Wfc + (size_t)col * 4);
#pragma unroll
        for (int r = 0; r < 4; r++) {
            out[(size_t)(rbase + r) * D_ + col] =
                acc[c][r] + px[r] * wf.x + py[r] * wf.y + pz[r] * wf.z + wf.w;
        }
    }
}

// ---------------------------------------------------------------------------
extern "C" void kernel_launch(void* const* d_in, const int* in_sizes, int n_in,
                              void* d_out, int out_size, void* d_ws, size_t ws_size,
                              hipStream_t stream)
{
    const float* points = (const float*)d_in[0];
    const float* voxel  = (const float*)d_in[1];
    const float* Wp  = (const float*)d_in[2];
    const float* bp  = (const float*)d_in[3];
    const float* Wq  = (const float*)d_in[4];
    const float* bq  = (const float*)d_in[5];
    const float* Wk  = (const float*)d_in[6];
    const float* bk  = (const float*)d_in[7];
    const float* Wv  = (const float*)d_in[8];
    const float* bv  = (const float*)d_in[9];
    const float* Wf  = (const float*)d_in[10];
    const float* bfb = (const float*)d_in[11];
    float* out = (float*)d_out;

    float* Wqc = (float*)d_ws;                         // [256][4] f32
    float* Wfc = Wqc + 256 * 4;                        // [256][4] f32
    unsigned short* k_g   = (unsigned short*)(Wfc + 256 * 4);
    unsigned short* vt_g  = k_g  + (size_t)KVROWS_ * D_;   // [b][h][dh][m]
    unsigned short* att_g = vt_g + (size_t)KVROWS_ * D_;

    g_projkv4<<<dim3(514), dim3(256), 0, stream>>>(voxel, Wp, bp, Wq, bq, Wk, bk,
                                                   Wv, bv, Wf, bfb, k_g, vt_g, Wqc, Wfc);
    k_attn10<<<dim3(B_ * H_ * (N_ / 128)), dim3(512), 0, stream>>>(points, Wqc, k_g, vt_g, att_g);
    g_fuse3 <<<dim3((ROWS_ / 64) * 4), dim3(256), 0, stream>>>(att_g, points, Wfc, Wf, out);
}

// Round 8
// 132.124 us; speedup vs baseline: 3.0173x; 1.0132x over previous
//
#include <hip/hip_runtime.h>

#define B_ 2
#define N_ 4096
#define M_ 2048
#define D_ 256
#define H_ 8
#define DH_ 32
#define ROWS_ (B_*N_)
#define KVROWS_ (B_*M_)
// SCALE * log2(e): q pre-scaled so softmax = exp2
#define PRE_ (0.17677669529663687f * 1.4426950408889634f)
#define CBASE_ 32.0f

typedef __attribute__((ext_vector_type(8))) short short8_t;
typedef __attribute__((ext_vector_type(4))) float float4_t;

#if defined(__has_builtin)
# if __has_builtin(__builtin_amdgcn_exp2f)
#  define EXP2F(x) __builtin_amdgcn_exp2f(x)
# else
#  define EXP2F(x) exp2f(x)
# endif
#else
# define EXP2F(x) exp2f(x)
#endif

// RTNE round-to-bf16 helper: rounded 32-bit word (bf16 in high half)
__device__ __forceinline__ unsigned int rne_u(float f) {
    union { float f; unsigned int u; } c;
    c.f = f;
    return c.u + 0x7FFFu + ((c.u >> 16) & 1u);
}

__device__ __forceinline__ unsigned short f2us(float f) {
    return (unsigned short)(rne_u(f) >> 16);
}

// pack two RTNE bf16: low16 = a, high16 = b  (single v_perm_b32 combine)
__device__ __forceinline__ unsigned int pack2rn(float a, float b) {
    return __builtin_amdgcn_perm(rne_u(b), rne_u(a), 0x07060302u);
}

// truncation pack (P tiles only; <=2^-8 rel err) — single v_perm_b32
__device__ __forceinline__ unsigned int pack2tr(float a, float b) {
    union { float f; unsigned int u; } x, y;
    x.f = a; y.f = b;
    return __builtin_amdgcn_perm(y.u, x.u, 0x07060302u);
}

__device__ __forceinline__ short8_t cvt8(float4 a, float4 b) {
    union { unsigned int u[4]; short8_t s; } c;
    c.u[0] = pack2rn(a.x, a.y);
    c.u[1] = pack2rn(a.z, a.w);
    c.u[2] = pack2rn(b.x, b.y);
    c.u[3] = pack2rn(b.z, b.w);
    return c.s;
}

// bijective XCD-aware block-id swizzle (valid when nwg % 8 == 0)
__device__ __forceinline__ int xcd_swz(int bid, int nwg) {
    const int cpx = nwg >> 3;
    return (bid & 7) * cpx + (bid >> 3);
}

// ---------------------------------------------------------------------------
// Stage NCOL x K fp32 weight block (source row stride LDSRC, col offset kof)
// into XOR-swizzled bf16 LDS.
// ---------------------------------------------------------------------------
template<int K, int NCOL, int LDSRC>
__device__ __forceinline__ void stageB2(const float* __restrict__ W, int col0, int kof,
                                        unsigned short* __restrict__ Bs, int tid)
{
    const int n = tid & (NCOL - 1), g = tid / NCOL;
    const int GROUPS = 256 / NCOL;
    const int CPT = (K / 8) / GROUPS;
    const float* src = W + (size_t)(col0 + n) * LDSRC + kof + g * (K / GROUPS);
#pragma unroll
    for (int ci = 0; ci < CPT; ci++) {
        int logc = g * CPT + ci;
        int phys = logc ^ (n & 7);
        short8_t v = cvt8(*(const float4*)(src + ci * 8), *(const float4*)(src + ci * 8 + 4));
        *(short8_t*)(Bs + (size_t)n * K + phys * 8) = v;
    }
}

template<int K>
__device__ __forceinline__ short8_t readB(const unsigned short* __restrict__ Bs,
                                          int c, int l16, int quad, int k0)
{
    int phys = ((k0 >> 3) + quad) ^ (l16 & 7);
    return *(const short8_t*)(Bs + (size_t)(16 * c + l16) * K + phys * 8);
}

// ---------------------------------------------------------------------------
// KV projection + weight-fold prep (r7 shape, unchanged).
// ---------------------------------------------------------------------------
__global__ __launch_bounds__(256) void g_projkv4(
    const float* __restrict__ voxel,
    const float* __restrict__ Wp, const float* __restrict__ bp,
    const float* __restrict__ Wq, const float* __restrict__ bq,
    const float* __restrict__ Wk, const float* __restrict__ bk,
    const float* __restrict__ Wv, const float* __restrict__ bv,
    const float* __restrict__ Wf, const float* __restrict__ bfb,
    unsigned short* __restrict__ k_g, unsigned short* __restrict__ vt_g,
    float* __restrict__ Wqc, float* __restrict__ Wfc)
{
    const int tid = threadIdx.x;
    const int wave = tid >> 6, lane = tid & 63, quad = lane >> 4, l16 = lane & 15;

    __shared__ unsigned short Bs[64 * 256];   // 32 KB

    const int bid = (int)blockIdx.x;
    if (bid < 512) {
        const int lbid = xcd_swz(bid, 512);
        const int row0 = (lbid >> 3) * 64;
        const int sub  = lbid & 7;
        const int col0 = (sub >> 1) * 64;
        const bool isV = sub & 1;

        stageB2<256, 64, 256>(isV ? Wv : Wk, col0, 0, Bs, tid);

        const float* arow = voxel + (size_t)(row0 + wave * 16 + l16) * D_;
        short8_t af[8];
#pragma unroll
        for (int i = 0; i < 8; i++)
            af[i] = cvt8(*(const float4*)(arow + i * 32 + quad * 8),
                         *(const float4*)(arow + i * 32 + quad * 8 + 4));

        float4_t acc[4];
#pragma unroll
        for (int c = 0; c < 4; c++) acc[c] = (float4_t){0.f, 0.f, 0.f, 0.f};
        __syncthreads();
#pragma unroll
        for (int i = 0; i < 8; i++)
#pragma unroll
            for (int c = 0; c < 4; c++)
                acc[c] = __builtin_amdgcn_mfma_f32_16x16x32_bf16(af[i], readB<256>(Bs, c, l16, quad, i * 32), acc[c], 0, 0, 0);

        if (!isV) {
#pragma unroll
            for (int c = 0; c < 4; c++) {
                int col = col0 + 16 * c + l16;
                float bbk = bk[col];
#pragma unroll
                for (int r = 0; r < 4; r++) {
                    int row = row0 + wave * 16 + quad * 4 + r;
                    k_g[(size_t)row * D_ + col] = f2us(acc[c][r] + bbk);
                }
            }
        } else {
            const int b = row0 / M_;
            const int m0 = row0 - b * M_ + wave * 16 + quad * 4;
#pragma unroll
            for (int c = 0; c < 4; c++) {
                int col = col0 + 16 * c + l16;
                float bbv = bv[col];
                int h = col >> 5, dh = col & 31;
                unsigned int u0 = pack2rn(acc[c][0] + bbv, acc[c][1] + bbv);
                unsigned int u1 = pack2rn(acc[c][2] + bbv, acc[c][3] + bbv);
                *(uint2*)(vt_g + (size_t)((b * H_ + h) * DH_ + dh) * M_ + m0) = make_uint2(u0, u1);
            }
        }
    } else {
        // ---- prep role: fold fan-in-3 weights in f32 (exact) ----
        const int role = bid - 512;               // 0: Wqc, 1: Wfc
        float* wps = (float*)Bs;                  // [256][4] staged Wp|bp
        *(float4*)(wps + tid * 4) = make_float4(Wp[tid * 3 + 0], Wp[tid * 3 + 1],
                                                Wp[tid * 3 + 2], bp[tid]);
        __syncthreads();
        const int col = tid;
        const float* wrow = role ? (Wf + (size_t)col * 512) : (Wq + (size_t)col * 256);
        float a0 = 0.f, a1 = 0.f, a2 = 0.f, ab = 0.f;
#pragma unroll 4
        for (int d = 0; d < 256; d += 4) {
            float4 wv = *(const float4*)(wrow + d);
            float4 w0 = *(const float4*)(wps + (d + 0) * 4);
            float4 w1 = *(const float4*)(wps + (d + 1) * 4);
            float4 w2 = *(const float4*)(wps + (d + 2) * 4);
            float4 w3 = *(const float4*)(wps + (d + 3) * 4);
            a0 += wv.x * w0.x + wv.y * w1.x + wv.z * w2.x + wv.w * w3.x;
            a1 += wv.x * w0.y + wv.y * w1.y + wv.z * w2.y + wv.w * w3.y;
            a2 += wv.x * w0.z + wv.y * w1.z + wv.z * w2.z + wv.w * w3.z;
            ab += wv.x * w0.w + wv.y * w1.w + wv.z * w2.w + wv.w * w3.w;
        }
        if (role == 0) {
            *(float4*)(Wqc + (size_t)col * 4) =
                make_float4(a0 * PRE_, a1 * PRE_, a2 * PRE_, (ab + bq[col]) * PRE_);
        } else {
            *(float4*)(Wfc + (size_t)col * 4) =
                make_float4(a0, a1, a2, ab + bfb[col]);
        }
    }
}

// ---------------------------------------------------------------------------
// MFMA flash attention v11: 128 q-rows/block, 512 threads (8 waves).
//  - permuted-K QK^T -> P directly in PV B-fragment order (r5 trick)
//  - 4-buffer LDS pipeline, ONE barrier per 2 steps (16 barriers total),
//    staging latency window doubled
//  - l-sum on the MFMA pipe: mfma(ones, pa/pb2, lacc) = full row-sum of P
//    (replaces 16 VALU adds/step + 2 end shuffles; same bf16 P as PV)
// LDS: Kt[4][64][40] 20 KB + Vt[4][32][72] 18 KB = 38 KB -> 2 blocks/CU.
// ---------------------------------------------------------------------------
__global__ __launch_bounds__(512) void k_attn11(
    const float* __restrict__ points, const float* __restrict__ Wqc,
    const unsigned short* __restrict__ k_g,
    const unsigned short* __restrict__ vt_g,
    unsigned short* __restrict__ att_g)
{
    const int tid = threadIdx.x;
    const int w = tid >> 6, lane = tid & 63, quad = lane >> 4, l16 = lane & 15;
    const int lbid = xcd_swz((int)blockIdx.x, B_ * H_ * (N_ / 128));
    const int nt = lbid & 31;             // N/128
    const int bh = lbid >> 5;             // b*8+h
    const int b = bh >> 3, h = bh & 7;
    const int n0 = nt * 128 + w * 16;

    __shared__ unsigned short Kt[4][64][40];   // 20 KB
    __shared__ unsigned short Vt[4][32][72];   // 18 KB

    const unsigned short* kbase = k_g + (size_t)(b * M_) * D_ + h * DH_;
    const unsigned short* vbase = vt_g + (size_t)(bh * DH_) * M_;

    // staging role: one 16B chunk per thread per step
    const bool isK = (tid < 256);
    const int kr = tid >> 2, kc = tid & 3;            // K: 64 rows x 4 chunks
    const int vr = (tid - 256) >> 3, vc = tid & 7;    // V: 32 rows x 8 chunks
    const int ksr = kr ^ ((kr & 8) >> 1);             // rho-permuted K LDS row

    const int gstep = isK ? 64 * D_ : 64;
    const unsigned short* gq = isK ? (kbase + (size_t)kr * D_ + kc * 8)
                                   : (vbase + (size_t)vr * M_ + vc * 8);
    unsigned short* ldst = isK ? (&Kt[0][0][0] + ksr * 40 + kc * 8)
                               : (&Vt[0][0][0] + vr * 72 + vc * 8);
    const int lstride = isK ? 2560 : 2304;            // buf stride in shorts

    // prologue: stage steps 0,1 into bufs 0,1
    *(short8_t*)ldst = *(const short8_t*)gq;
    gq += gstep;
    *(short8_t*)(ldst + lstride) = *(const short8_t*)gq;

    // permuted K-row read indices (rho applied; XOR safe: bit2 never carries)
    const int rbas = 8 * (l16 >> 2) + (l16 & 3);
    const int rx = l16 & 4;
    int krow[4];
#pragma unroll
    for (int t = 0; t < 4; t++)
        krow[t] = (rbas + 4 * (t & 1) + 32 * (t >> 1)) ^ rx;

    // q inline: row = b*N_ + n0 + l16, cols h*32 + quad*8 + j  (f32-exact)
    const size_t qrow = (size_t)(b * N_ + n0 + l16);
    const float p0 = points[qrow * 3 + 0];
    const float p1 = points[qrow * 3 + 1];
    const float p2 = points[qrow * 3 + 2];
    float q8[8];
#pragma unroll
    for (int j = 0; j < 8; j++) {
        float4 wc = *(const float4*)(Wqc + (size_t)(h * DH_ + quad * 8 + j) * 4);
        q8[j] = p0 * wc.x + p1 * wc.y + p2 * wc.z + wc.w;
    }
    short8_t qf = cvt8(make_float4(q8[0], q8[1], q8[2], q8[3]),
                       make_float4(q8[4], q8[5], q8[6], q8[7]));

    // all-ones bf16 A-fragment for the l-sum MFMA
    short8_t ones;
#pragma unroll
    for (int j = 0; j < 8; j++) ones[j] = (short)0x3F80;

    float4_t od0 = {0.f, 0.f, 0.f, 0.f};
    float4_t od1 = {0.f, 0.f, 0.f, 0.f};
    float4_t lacc = {0.f, 0.f, 0.f, 0.f};

    const float4_t zc = {-CBASE_, -CBASE_, -CBASE_, -CBASE_};

    __syncthreads();

#define STEPC(KB_, VB_)                                                         \
    do {                                                                        \
        float4_t st[4];                                                         \
        _Pragma("unroll")                                                       \
        for (int t = 0; t < 4; t++) {                                           \
            short8_t kf = *(const short8_t*)&Kt[KB_][krow[t]][quad * 8];        \
            st[t] = __builtin_amdgcn_mfma_f32_16x16x32_bf16(kf, qf, zc, 0, 0, 0); \
        }                                                                       \
        unsigned int uu[4][2];                                                  \
        _Pragma("unroll")                                                       \
        for (int t = 0; t < 4; t++) {                                           \
            float e0 = EXP2F(st[t][0]);                                         \
            float e1 = EXP2F(st[t][1]);                                         \
            float e2 = EXP2F(st[t][2]);                                         \
            float e3 = EXP2F(st[t][3]);                                         \
            uu[t][0] = pack2tr(e0, e1);                                         \
            uu[t][1] = pack2tr(e2, e3);                                         \
        }                                                                       \
        union { unsigned int u[4]; short8_t s; } pa, pb2;                       \
        pa.u[0]  = uu[0][0]; pa.u[1]  = uu[0][1];                               \
        pa.u[2]  = uu[1][0]; pa.u[3]  = uu[1][1];                               \
        pb2.u[0] = uu[2][0]; pb2.u[1] = uu[2][1];                               \
        pb2.u[2] = uu[3][0]; pb2.u[3] = uu[3][1];                               \
        lacc = __builtin_amdgcn_mfma_f32_16x16x32_bf16(ones, pa.s,  lacc, 0, 0, 0); \
        lacc = __builtin_amdgcn_mfma_f32_16x16x32_bf16(ones, pb2.s, lacc, 0, 0, 0); \
        short8_t vf00 = *(const short8_t*)&Vt[VB_][l16][quad * 8];              \
        short8_t vf01 = *(const short8_t*)&Vt[VB_][l16][32 + quad * 8];         \
        short8_t vf10 = *(const short8_t*)&Vt[VB_][16 + l16][quad * 8];         \
        short8_t vf11 = *(const short8_t*)&Vt[VB_][16 + l16][32 + quad * 8];    \
        od0 = __builtin_amdgcn_mfma_f32_16x16x32_bf16(vf00, pa.s,  od0, 0, 0, 0); \
        od0 = __builtin_amdgcn_mfma_f32_16x16x32_bf16(vf01, pb2.s, od0, 0, 0, 0); \
        od1 = __builtin_amdgcn_mfma_f32_16x16x32_bf16(vf10, pa.s,  od1, 0, 0, 0); \
        od1 = __builtin_amdgcn_mfma_f32_16x16x32_bf16(vf11, pb2.s, od1, 0, 0, 0); \
    } while (0)

#pragma unroll 2
    for (int s = 0; s < M_ / 64; s += 2) {
        const bool m0 = (s + 2 < M_ / 64);
        const bool m1 = (s + 3 < M_ / 64);
        short8_t nxt0, nxt1;
        if (m0) { gq += gstep; nxt0 = *(const short8_t*)gq; }
        if (m1) { gq += gstep; nxt1 = *(const short8_t*)gq; }

        STEPC((s) & 3, (s) & 3);
        STEPC((s + 1) & 3, (s + 1) & 3);

        if (m0) *(short8_t*)(ldst + ((s + 2) & 3) * lstride) = nxt0;
        if (m1) *(short8_t*)(ldst + ((s + 3) & 3) * lstride) = nxt1;
        __syncthreads();
    }
#undef STEPC

    const float inv = 1.0f / lacc[0];

    unsigned short* ob = att_g + (size_t)(b * N_ + n0 + l16) * D_ + h * DH_;
    {
        unsigned int u0 = pack2rn(od0[0] * inv, od0[1] * inv);
        unsigned int u1 = pack2rn(od0[2] * inv, od0[3] * inv);
        *(uint2*)(ob + quad * 4) = make_uint2(u0, u1);
        unsigned int u2 = pack2rn(od1[0] * inv, od1[1] * inv);
        unsigned int u3 = pack2rn(od1[2] * inv, od1[3] * inv);
        *(uint2*)(ob + 16 + quad * 4) = make_uint2(u2, u3);
    }
}

// ---------------------------------------------------------------------------
// Fuse: out = att@Wf2.T + points@Wfc.T (bias folded), fp32 out.
// 64x64 tiles (512 blocks), r7 shape unchanged.
// ---------------------------------------------------------------------------
__global__ __launch_bounds__(256) void g_fuse3(
    const unsigned short* __restrict__ att_g,
    const float* __restrict__ points, const float* __restrict__ Wfc,
    const float* __restrict__ Wf,
    float* __restrict__ out)
{
    const int tid = threadIdx.x;
    const int wave = tid >> 6, lane = tid & 63, quad = lane >> 4, l16 = lane & 15;
    const int lbid = xcd_swz((int)blockIdx.x, (ROWS_ / 64) * 4);
    const int row0 = (lbid >> 2) * 64;
    const int col0 = (lbid & 3) * 64;

    __shared__ unsigned short Bs[64 * 256];  // 32 KB (Wf cols 256..511)

    stageB2<256, 64, 512>(Wf, col0, 256, Bs, tid);
    __syncthreads();

    float4_t acc[4];
#pragma unroll
    for (int c = 0; c < 4; c++) acc[c] = (float4_t){0.f, 0.f, 0.f, 0.f};

    const size_t arow = (size_t)(row0 + wave * 16 + l16) * D_;
#pragma unroll
    for (int k0 = 0; k0 < 256; k0 += 32) {
        short8_t af = *(const short8_t*)(att_g + arow + k0 + quad * 8);
#pragma unroll
        for (int c = 0; c < 4; c++)
            acc[c] = __builtin_amdgcn_mfma_f32_16x16x32_bf16(af, readB<256>(Bs, c, l16, quad, k0), acc[c], 0, 0, 0);
    }

    const int rbase = row0 + wave * 16 + quad * 4;
    float px[4], py[4], pz[4];
#pragma unroll
    for (int r = 0; r < 4; r++) {
        px[r] = points[(size_t)(rbase + r) * 3 + 0];
        py[r] = points[(size_t)(rbase + r) * 3 + 1];
        pz[r] = points[(size_t)(rbase + r) * 3 + 2];
    }
#pragma unroll
    for (int c = 0; c < 4; c++) {
        int col = col0 + 16 * c + l16;
        float4 wf = *(const float4*)(Wfc + (size_t)col * 4);
#pragma unroll
        for (int r = 0; r < 4; r++) {
            out[(size_t)(rbase + r) * D_ + col] =
                acc[c][r] + px[r] * wf.x + py[r] * wf.y + pz[r] * wf.z + wf.w;
        }
    }
}

// ---------------------------------------------------------------------------
extern "C" void kernel_launch(void* const* d_in, const int* in_sizes, int n_in,
                              void* d_out, int out_size, void* d_ws, size_t ws_size,
                              hipStream_t stream)
{
    const float* points = (const float*)d_in[0];
    const float* voxel  = (const float*)d_in[1];
    const float* Wp  = (const float*)d_in[2];
    const float* bp  = (const float*)d_in[3];
    const float* Wq  = (const float*)d_in[4];
    const float* bq  = (const float*)d_in[5];
    const float* Wk  = (const float*)d_in[6];
    const float* bk  = (const float*)d_in[7];
    const float* Wv  = (const float*)d_in[8];
    const float* bv  = (const float*)d_in[9];
    const float* Wf  = (const float*)d_in[10];
    const float* bfb = (const float*)d_in[11];
    float* out = (float*)d_out;

    float* Wqc = (float*)d_ws;                         // [256][4] f32
    float* Wfc = Wqc + 256 * 4;                        // [256][4] f32
    unsigned short* k_g   = (unsigned short*)(Wfc + 256 * 4);
    unsigned short* vt_g  = k_g  + (size_t)KVROWS_ * D_;   // [b][h][dh][m]
    unsigned short* att_g = vt_g + (size_t)KVROWS_ * D_;

    g_projkv4<<<dim3(514), dim3(256), 0, stream>>>(voxel, Wp, bp, Wq, bq, Wk, bk,
                                                   Wv, bv, Wf, bfb, k_g, vt_g, Wqc, Wfc);
    k_attn11<<<dim3(B_ * H_ * (N_ / 128)), dim3(512), 0, stream>>>(points, Wqc, k_g, vt_g, att_g);
    g_fuse3 <<<dim3((ROWS_ / 64) * 4), dim3(256), 0, stream>>>(att_g, points, Wfc, Wf, out);
}